// Round 10
// baseline (2578.478 us; speedup 1.0000x reference)
//
#include <hip/hip_runtime.h>
#include <hip/hip_bf16.h>

// LSTM: B=64, T=2048, D=128, H=128, gates 4H=512.
// SINGLE fused kernel: 64 blocks x 512 threads (8 waves), wpe(2,2).
// R9 lesson: RNN time = T x step_latency, independent of batches/block.
// This round removes the separate xg GEMM (~250us + HBM traffic) by
// computing xg(t+2) = bias + x[t+2]@Wx via MFMA INSIDE step t, into the
// f32x4 accs that become the C-operand init of step t+2's h-MFMA chain.
// Wave w owns gate cols {gc*128 + w*16+cl}, gc=0..3 (i,f,g,o for hu).
// Wh frags 64 VGPR + Wx frags 64 VGPR + xg ping-pong 32 VGPR, all resident.
// Per step: 16 h-MFMA (C-init = xg) + 16 xg-MFMA (independent, fills waits);
// c/h update fully in-register; 1 raw s_barrier + lgkmcnt(0) per step.

#define B_ 64
#define T_ 2048
#define D_ 128
#define H_ 128
#define G_ 512  // 4*H

typedef __bf16 v8bf __attribute__((ext_vector_type(8)));
typedef float f32x4 __attribute__((ext_vector_type(4)));

__device__ __forceinline__ float fast_exp2(float x) { return __builtin_amdgcn_exp2f(x); }
__device__ __forceinline__ float fast_rcp(float x)  { return __builtin_amdgcn_rcpf(x); }
__device__ __forceinline__ float sigmoid_(float x) {
    return fast_rcp(1.0f + fast_exp2(x * -1.44269504088896341f));
}
__device__ __forceinline__ float tanh_(float x) {
    // tanh(x) = 1 - 2/(1+2^(x*2*log2e)); saturates correctly at +-inf.
    return 1.0f - 2.0f * fast_rcp(1.0f + fast_exp2(x * 2.88539008177792682f));
}
__device__ __forceinline__ unsigned short f2bf(float f) {
    union { float f; unsigned u; } v; v.f = f;
    unsigned r = v.u + 0x7FFFu + ((v.u >> 16) & 1u);  // RNE
    return (unsigned short)(r >> 16);
}

__global__ void __launch_bounds__(512)
__attribute__((amdgpu_waves_per_eu(2, 2)))
lstm_fused(const float* __restrict__ x, const float* __restrict__ Wx,
           const float* __restrict__ Wh, const float* __restrict__ bias,
           float* __restrict__ hs, float* __restrict__ cs) {
    const int b    = blockIdx.x;
    const int tid  = threadIdx.x;
    const int w    = tid >> 6;     // wave 0..7
    const int lane = tid & 63;
    const int q    = lane >> 4;    // k-quarter
    const int cl   = lane & 15;
    const int kb   = q * 8;
    const int hu   = w * 16 + cl;  // hidden unit owned

    __shared__ __align__(16) unsigned short h_u16[2][H_];

    // ---- one-time: Wh and Wx B-fragments (16+16 frags = 128 VGPRs) ----
    v8bf whf[4][4], wxf[4][4];
#pragma unroll
    for (int kk = 0; kk < 4; ++kk) {
#pragma unroll
        for (int gc = 0; gc < 4; ++gc) {
            union { unsigned short s[8]; v8bf v; } uh, ux;
#pragma unroll
            for (int j = 0; j < 8; ++j) {
                uh.s[j] = f2bf(Wh[(size_t)(kk * 32 + kb + j) * G_ + gc * 128 + hu]);
                ux.s[j] = f2bf(Wx[(size_t)(kk * 32 + kb + j) * G_ + gc * 128 + hu]);
            }
            whf[kk][gc] = uh.v;
            wxf[kk][gc] = ux.v;
        }
    }
    const float bs0 = bias[0 * 128 + hu];
    const float bs1 = bias[1 * 128 + hu];
    const float bs2 = bias[2 * 128 + hu];
    const float bs3 = bias[3 * 128 + hu];

    float c = 0.0f;
    if (tid < H_) h_u16[0][tid] = 0;  // h_0 = 0
    __syncthreads();

    const float* xb = x + (size_t)b * T_ * D_;

// xg production: XA{0..3} = bias + x[TN]@Wx for this lane's 4 gate cols.
// x loaded f32 (L1-hot 512B row), packed to bf16 via v_cvt_pk_bf16_f32.
#define XPROD(XA0, XA1, XA2, XA3, TN)                                          \
    {                                                                          \
        const float* xr_ = xb + (size_t)(TN) * D_;                             \
        v8bf xf_[4];                                                           \
        _Pragma("unroll")                                                      \
        for (int kk = 0; kk < 4; ++kk) {                                       \
            float4 lo_ = *(const float4*)&xr_[kk * 32 + kb];                   \
            float4 hi_ = *(const float4*)&xr_[kk * 32 + kb + 4];               \
            union { unsigned u[4]; v8bf v; } pk_;                              \
            asm("v_cvt_pk_bf16_f32 %0, %1, %2" : "=v"(pk_.u[0]) : "v"(lo_.x), "v"(lo_.y)); \
            asm("v_cvt_pk_bf16_f32 %0, %1, %2" : "=v"(pk_.u[1]) : "v"(lo_.z), "v"(lo_.w)); \
            asm("v_cvt_pk_bf16_f32 %0, %1, %2" : "=v"(pk_.u[2]) : "v"(hi_.x), "v"(hi_.y)); \
            asm("v_cvt_pk_bf16_f32 %0, %1, %2" : "=v"(pk_.u[3]) : "v"(hi_.z), "v"(hi_.w)); \
            xf_[kk] = pk_.v;                                                   \
        }                                                                      \
        f32x4 t0_ = {bs0, bs0, bs0, bs0};                                      \
        f32x4 t1_ = {bs1, bs1, bs1, bs1};                                      \
        f32x4 t2_ = {bs2, bs2, bs2, bs2};                                      \
        f32x4 t3_ = {bs3, bs3, bs3, bs3};                                      \
        _Pragma("unroll")                                                      \
        for (int kk = 0; kk < 4; ++kk) {                                       \
            t0_ = __builtin_amdgcn_mfma_f32_16x16x32_bf16(xf_[kk], wxf[kk][0], t0_, 0, 0, 0); \
            t1_ = __builtin_amdgcn_mfma_f32_16x16x32_bf16(xf_[kk], wxf[kk][1], t1_, 0, 0, 0); \
            t2_ = __builtin_amdgcn_mfma_f32_16x16x32_bf16(xf_[kk], wxf[kk][2], t2_, 0, 0, 0); \
            t3_ = __builtin_amdgcn_mfma_f32_16x16x32_bf16(xf_[kk], wxf[kk][3], t3_, 0, 0, 0); \
        }                                                                      \
        XA0 = t0_; XA1 = t1_; XA2 = t2_; XA3 = t3_;                            \
    }

    // prologue: xg(0) and xg(1)
    f32x4 xa00, xa01, xa02, xa03, xa10, xa11, xa12, xa13;
    XPROD(xa00, xa01, xa02, xa03, 0)
    XPROD(xa10, xa11, xa12, xa13, 1)

#define RNN_STEP(XA0, XA1, XA2, XA3, TCUR, PR, PW)                             \
    {                                                                          \
        f32x4 a0 = XA0, a1 = XA1, a2 = XA2, a3 = XA3;                          \
        _Pragma("unroll")                                                      \
        for (int kk = 0; kk < 4; ++kk) {                                       \
            v8bf ha = *(const v8bf*)&h_u16[PR][kk * 32 + kb];                  \
            a0 = __builtin_amdgcn_mfma_f32_16x16x32_bf16(ha, whf[kk][0], a0, 0, 0, 0); \
            a1 = __builtin_amdgcn_mfma_f32_16x16x32_bf16(ha, whf[kk][1], a1, 0, 0, 0); \
            a2 = __builtin_amdgcn_mfma_f32_16x16x32_bf16(ha, whf[kk][2], a2, 0, 0, 0); \
            a3 = __builtin_amdgcn_mfma_f32_16x16x32_bf16(ha, whf[kk][3], a3, 0, 0, 0); \
        }                                                                      \
        /* produce xg(TCUR+2) into this slot (independent; fills waits) */     \
        { int tn_ = (TCUR) + 2; if (tn_ >= T_) tn_ = T_ - 1;                   \
          XPROD(XA0, XA1, XA2, XA3, tn_) }                                     \
        float iv = sigmoid_(a0[0]);                                            \
        float fv = sigmoid_(a1[0]);                                            \
        float gv = tanh_(a2[0]);                                               \
        float ov = sigmoid_(a3[0]);                                            \
        c = fmaf(fv, c, iv * gv);                                              \
        float hnv = ov * tanh_(c);                                             \
        if (q == 0) {                                                          \
            h_u16[PW][hu] = f2bf(hnv);                                         \
            size_t off = ((size_t)b * T_ + (size_t)(TCUR)) * H_ + hu;          \
            hs[off] = hnv; cs[off] = c;                                        \
        }                                                                      \
        asm volatile("s_waitcnt lgkmcnt(0)\n\ts_barrier" ::: "memory");        \
    }

#pragma unroll 1
    for (int t = 0; t < T_; t += 2) {
        RNN_STEP(xa00, xa01, xa02, xa03, t,     0, 1)
        RNN_STEP(xa10, xa11, xa12, xa13, t + 1, 1, 0)
    }
#undef RNN_STEP
#undef XPROD
}

extern "C" void kernel_launch(void* const* d_in, const int* in_sizes, int n_in,
                              void* d_out, int out_size, void* d_ws, size_t ws_size,
                              hipStream_t stream) {
    const float* x    = (const float*)d_in[0];  // [64,2048,128]
    const float* Wx   = (const float*)d_in[1];  // [128,512]
    const float* Wh   = (const float*)d_in[2];  // [128,512]
    const float* bias = (const float*)d_in[3];  // [512]

    float* hs = (float*)d_out;                  // [64,2048,128]
    float* cs = hs + (size_t)B_ * T_ * H_;      // [64,2048,128]

    (void)d_ws; (void)ws_size; (void)in_sizes; (void)n_in; (void)out_size;
    lstm_fused<<<B_, 512, 0, stream>>>(x, Wx, Wh, bias, hs, cs);
}

// Round 11
// 1278.820 us; speedup vs baseline: 2.0163x; 2.0163x over previous
//
#include <hip/hip_runtime.h>
#include <hip/hip_bf16.h>

// LSTM: B=64, T=2048, D=128, H=128, gates 4H=512.
// R10 lesson: allocator hard-caps at 128 VGPRs; fused kernel (ask ~200)
// spilled and regressed 3.2x. Reverted to split structure (R8 RNN):
//  K0: wxt pre-kernel: Wx f32[128][512] -> bf16 wxt[col][k] (frag-friendly)
//  K1: xg GEMM via bf16 MFMA, M=16 rows used (R10 precision path, passed)
//  K2: R8 RNN + 2+2 MFMA chain split + s_setprio around MFMA cluster.

#define B_ 64
#define T_ 2048
#define D_ 128
#define H_ 128
#define G_ 512  // 4*H

typedef __bf16 v8bf __attribute__((ext_vector_type(8)));
typedef float f32x4 __attribute__((ext_vector_type(4)));

__device__ __forceinline__ float fast_exp2(float x) { return __builtin_amdgcn_exp2f(x); }
__device__ __forceinline__ float fast_rcp(float x)  { return __builtin_amdgcn_rcpf(x); }
__device__ __forceinline__ float sigmoid_(float x) {
    return fast_rcp(1.0f + fast_exp2(x * -1.44269504088896341f));
}
__device__ __forceinline__ float tanh_(float x) {
    // tanh(x) = 1 - 2/(1+2^(x*2*log2e)); saturates correctly at +-inf.
    return 1.0f - 2.0f * fast_rcp(1.0f + fast_exp2(x * 2.88539008177792682f));
}
__device__ __forceinline__ unsigned short f2bf(float f) {
    union { float f; unsigned u; } v; v.f = f;
    unsigned r = v.u + 0x7FFFu + ((v.u >> 16) & 1u);  // RNE
    return (unsigned short)(r >> 16);
}

// ---------------- K0: Wx -> bf16 transposed wxt[col][k] ----------------
// 32 blocks x 256 thr; thread handles one (col, k-octet): 8 strided reads,
// one 16B write.
__global__ void __launch_bounds__(256)
wxt_kernel(const float* __restrict__ Wx, unsigned short* __restrict__ wxt) {
    int t = blockIdx.x * 256 + threadIdx.x;   // 0..8191
    int col = t >> 4;            // 0..511
    int k0  = (t & 15) * 8;      // 0..120
    union { unsigned short s[8]; v8bf v; } u;
#pragma unroll
    for (int j = 0; j < 8; ++j) u.s[j] = f2bf(Wx[(size_t)(k0 + j) * G_ + col]);
    *(v8bf*)&wxt[(size_t)col * D_ + k0] = u.v;
}

// ---------------- K1: xg GEMM via MFMA ----------------
// grid (B*C)/16 blocks x 256 thr (4 waves). Block: 16 rows x 512 cols.
// Wave w: cols [w*128, w*128+128) = 8 N-tiles. M=16 rows of x (bf16).
__global__ void __launch_bounds__(256)
xg_gemm_mfma(const float* __restrict__ x, const unsigned short* __restrict__ wxt,
             const float* __restrict__ bias, float* __restrict__ xg,
             int t0, int C) {
    const int tid  = threadIdx.x;
    const int w    = tid >> 6;
    const int lane = tid & 63;
    const int q    = lane >> 4;
    const int cl   = lane & 15;
    const int kb   = q * 8;

    const int block_row = blockIdx.x * 16;     // in [0, B*C)
    const int b  = block_row / C;
    const int tl = block_row - b * C;

    // A-frags: rows = block rows, lane row = cl. af[kk] = x[row][kk*32+kb..+7]
    const float* xr = x + ((size_t)b * T_ + (size_t)(t0 + tl) + cl) * D_;
    v8bf af[4];
#pragma unroll
    for (int kk = 0; kk < 4; ++kk) {
        float4 lo = *(const float4*)&xr[kk * 32 + kb];
        float4 hi = *(const float4*)&xr[kk * 32 + kb + 4];
        union { unsigned u[4]; v8bf v; } pk;
        asm("v_cvt_pk_bf16_f32 %0, %1, %2" : "=v"(pk.u[0]) : "v"(lo.x), "v"(lo.y));
        asm("v_cvt_pk_bf16_f32 %0, %1, %2" : "=v"(pk.u[1]) : "v"(lo.z), "v"(lo.w));
        asm("v_cvt_pk_bf16_f32 %0, %1, %2" : "=v"(pk.u[2]) : "v"(hi.x), "v"(hi.y));
        asm("v_cvt_pk_bf16_f32 %0, %1, %2" : "=v"(pk.u[3]) : "v"(hi.z), "v"(hi.w));
        af[kk] = pk.v;
    }

    // acc init = bias[col]
    f32x4 acc[8];
#pragma unroll
    for (int n = 0; n < 8; ++n) {
        float bv = bias[w * 128 + n * 16 + cl];
        acc[n] = (f32x4){bv, bv, bv, bv};
    }

#pragma unroll
    for (int kk = 0; kk < 4; ++kk) {
#pragma unroll
        for (int n = 0; n < 8; ++n) {
            v8bf bf = *(const v8bf*)&wxt[(size_t)(w * 128 + n * 16 + cl) * D_ + kk * 32 + kb];
            acc[n] = __builtin_amdgcn_mfma_f32_16x16x32_bf16(af[kk], bf, acc[n], 0, 0, 0);
        }
    }

    // store: rows q*4+r, col w*128+n*16+cl
#pragma unroll
    for (int n = 0; n < 8; ++n) {
        int col = w * 128 + n * 16 + cl;
#pragma unroll
        for (int r = 0; r < 4; ++r)
            xg[(size_t)(block_row + q * 4 + r) * G_ + col] = acc[n][r];
    }
}

// ---------------- K2: recurrence via MFMA (R8 + chain split + setprio) ----------------
__global__ void __launch_bounds__(512)
__attribute__((amdgpu_waves_per_eu(2, 2)))
lstm_rnn_mfma(const float* __restrict__ xg, const float* __restrict__ Wh,
              float* __restrict__ hs, float* __restrict__ cs,
              float* __restrict__ hstate, float* __restrict__ cstate,
              int t0, int C) {
    const int b    = blockIdx.x;
    const int tid  = threadIdx.x;
    const int w    = tid >> 6;     // wave 0..7
    const int lane = tid & 63;
    const int q    = lane >> 4;    // k-quarter
    const int cl   = lane & 15;
    const int kb   = q * 8;
    const int hu   = w * 16 + cl;  // hidden unit owned

    __shared__ __align__(16) unsigned short h_u16[2][H_];

    // one-time: Wh B-fragments (16 frags = 64 VGPRs)
    v8bf whf[4][4];
#pragma unroll
    for (int kk = 0; kk < 4; ++kk) {
#pragma unroll
        for (int gc = 0; gc < 4; ++gc) {
            union { unsigned short s[8]; v8bf v; } uw;
#pragma unroll
            for (int j = 0; j < 8; ++j)
                uw.s[j] = f2bf(Wh[(size_t)(kk * 32 + kb + j) * G_ + gc * 128 + hu]);
            whf[kk][gc] = uw.v;
        }
    }

    float c = 0.0f;
    if (t0 > 0) c = cstate[b * H_ + hu];
    if (tid < H_) h_u16[0][tid] = f2bf((t0 > 0) ? hstate[b * H_ + tid] : 0.0f);
    __syncthreads();  // once per chunk

    const float* xgb = xg + (size_t)b * C * G_;

    // 4-step-deep xg prefetch in named registers: xp{s}{gate}
#define LOADX(s, T_IDX) \
    float xp##s##0, xp##s##1, xp##s##2, xp##s##3; \
    { const float* xp_ = xgb + (size_t)(T_IDX) * G_; \
      xp##s##0 = xp_[hu];       xp##s##1 = xp_[128 + hu]; \
      xp##s##2 = xp_[256 + hu]; xp##s##3 = xp_[384 + hu]; }
    LOADX(0, 0) LOADX(1, 1) LOADX(2, 2) LOADX(3, 3)
#undef LOADX

#define RNN_STEP(PX0, PX1, PX2, PX3, TCUR, PR, PW)                             \
    {                                                                          \
        f32x4 a0a = {0,0,0,0}, a1a = {0,0,0,0}, a2a = {0,0,0,0}, a3a = {0,0,0,0}; \
        f32x4 a0b = {0,0,0,0}, a1b = {0,0,0,0}, a2b = {0,0,0,0}, a3b = {0,0,0,0}; \
        __builtin_amdgcn_s_setprio(1);                                         \
        _Pragma("unroll")                                                      \
        for (int kk = 0; kk < 2; ++kk) {                                       \
            v8bf ha = *(const v8bf*)&h_u16[PR][kk * 32 + kb];                  \
            a0a = __builtin_amdgcn_mfma_f32_16x16x32_bf16(ha, whf[kk][0], a0a, 0, 0, 0); \
            a1a = __builtin_amdgcn_mfma_f32_16x16x32_bf16(ha, whf[kk][1], a1a, 0, 0, 0); \
            a2a = __builtin_amdgcn_mfma_f32_16x16x32_bf16(ha, whf[kk][2], a2a, 0, 0, 0); \
            a3a = __builtin_amdgcn_mfma_f32_16x16x32_bf16(ha, whf[kk][3], a3a, 0, 0, 0); \
        }                                                                      \
        _Pragma("unroll")                                                      \
        for (int kk = 2; kk < 4; ++kk) {                                       \
            v8bf ha = *(const v8bf*)&h_u16[PR][kk * 32 + kb];                  \
            a0b = __builtin_amdgcn_mfma_f32_16x16x32_bf16(ha, whf[kk][0], a0b, 0, 0, 0); \
            a1b = __builtin_amdgcn_mfma_f32_16x16x32_bf16(ha, whf[kk][1], a1b, 0, 0, 0); \
            a2b = __builtin_amdgcn_mfma_f32_16x16x32_bf16(ha, whf[kk][2], a2b, 0, 0, 0); \
            a3b = __builtin_amdgcn_mfma_f32_16x16x32_bf16(ha, whf[kk][3], a3b, 0, 0, 0); \
        }                                                                      \
        __builtin_amdgcn_s_setprio(0);                                         \
        float iv = sigmoid_(a0a[0] + a0b[0] + PX0);                            \
        float fv = sigmoid_(a1a[0] + a1b[0] + PX1);                            \
        float gv = tanh_(a2a[0] + a2b[0] + PX2);                               \
        float ov = sigmoid_(a3a[0] + a3b[0] + PX3);                            \
        c = fmaf(fv, c, iv * gv);                                              \
        float hnv = ov * tanh_(c);                                             \
        { int pf = ((TCUR) + 4 < C) ? ((TCUR) + 4) : (C - 1);                  \
          const float* xp_ = xgb + (size_t)pf * G_;                            \
          PX0 = xp_[hu];       PX1 = xp_[128 + hu];                            \
          PX2 = xp_[256 + hu]; PX3 = xp_[384 + hu]; }                          \
        if (q == 0) {                                                          \
            h_u16[PW][hu] = f2bf(hnv);                                         \
            size_t off = ((size_t)b * T_ + (size_t)(t0 + (TCUR))) * H_ + hu;   \
            hs[off] = hnv; cs[off] = c;                                        \
        }                                                                      \
        asm volatile("s_waitcnt lgkmcnt(0)\n\ts_barrier" ::: "memory");        \
    }

    for (int t = 0; t < C; t += 4) {  // C is a multiple of 64
        RNN_STEP(xp00, xp01, xp02, xp03, t,     0, 1)
        RNN_STEP(xp10, xp11, xp12, xp13, t + 1, 1, 0)
        RNN_STEP(xp20, xp21, xp22, xp23, t + 2, 0, 1)
        RNN_STEP(xp30, xp31, xp32, xp33, t + 3, 1, 0)
    }
#undef RNN_STEP

    if (q == 0) cstate[b * H_ + hu] = c;
    // final h in buf 0 (C multiple of 4; last step wrote PW=0)
    if (tid < H_) {
        unsigned ui = ((unsigned)h_u16[0][tid]) << 16;
        float hf; __builtin_memcpy(&hf, &ui, 4);
        hstate[b * H_ + tid] = hf;
    }
}

extern "C" void kernel_launch(void* const* d_in, const int* in_sizes, int n_in,
                              void* d_out, int out_size, void* d_ws, size_t ws_size,
                              hipStream_t stream) {
    const float* x    = (const float*)d_in[0];  // [64,2048,128]
    const float* Wx   = (const float*)d_in[1];  // [128,512]
    const float* Wh   = (const float*)d_in[2];  // [128,512]
    const float* bias = (const float*)d_in[3];  // [512]

    float* hs = (float*)d_out;                         // [64,2048,128]
    float* cs = hs + (size_t)B_ * T_ * H_;             // [64,2048,128]

    float* hstate = (float*)d_ws;                      // [64,128]
    float* cstate = hstate + B_ * H_;                  // [64,128]
    unsigned short* wxt = (unsigned short*)(cstate + B_ * H_);  // [512][128] bf16
    float* xg = (float*)(wxt + (size_t)G_ * D_);       // chunk scratch [B][C][512]

    const size_t head_bytes = (size_t)2 * B_ * H_ * 4 + (size_t)G_ * D_ * 2;
    size_t avail_bytes = (ws_size > head_bytes) ? (ws_size - head_bytes) : 0;
    const size_t bytes_per_t = (size_t)B_ * G_ * sizeof(float);

    int C = (int)(avail_bytes / bytes_per_t);
    if (C > T_) C = T_;
    C &= ~63;
    if (C < 64) C = 64;

    wxt_kernel<<<32, 256, 0, stream>>>(Wx, wxt);

    for (int t0 = 0; t0 < T_; t0 += C) {
        int Ci = (T_ - t0 < C) ? (T_ - t0) : C;
        dim3 ggrid((B_ * Ci) / 16);
        xg_gemm_mfma<<<ggrid, 256, 0, stream>>>(x, wxt, bias, xg, t0, Ci);
        lstm_rnn_mfma<<<B_, 512, 0, stream>>>(xg, Wh, hs, cs, hstate, cstate, t0, Ci);
    }
}